// Round 1
// baseline (581.400 us; speedup 1.0000x reference)
//
#include <hip/hip_runtime.h>
#include <hip/hip_bf16.h>
#include <math.h>

#define B_ 2
#define T_ 2048
#define C_ 768
#define H_ 12
#define D_ 64
#define HID_ 3072
#define NROW 4096   // B*T
#define N3C 2304    // 3*C

typedef short bf16x8 __attribute__((ext_vector_type(8)));
typedef float f32x4 __attribute__((ext_vector_type(4)));
typedef unsigned short u16;
typedef unsigned int u32;

__device__ inline u16 f2bf(float f) {
    u32 u = __float_as_uint(f);
    u32 r = (u + 0x7fffu + ((u >> 16) & 1u)) >> 16;  // RNE
    return (u16)r;
}

// ---------------- weight / activation f32 -> bf16 convert ----------------
__global__ __launch_bounds__(256) void cvt_bf16_kernel(const float* __restrict__ s,
                                                       u16* __restrict__ d, int n) {
    int i = (blockIdx.x * 256 + threadIdx.x) * 4;
    if (i >= n) return;
    float4 v = *(const float4*)(s + i);
    ushort4 o;
    o.x = f2bf(v.x); o.y = f2bf(v.y); o.z = f2bf(v.z); o.w = f2bf(v.w);
    *(ushort4*)(d + i) = o;
}

// ---------------- LayerNorm (f32 in, bf16 out), one block per row ----------------
__global__ __launch_bounds__(256) void ln_kernel(const float* __restrict__ x,
                                                 const float* __restrict__ g,
                                                 const float* __restrict__ b,
                                                 u16* __restrict__ out) {
    int row = blockIdx.x, t = threadIdx.x;
    const float* xr = x + (size_t)row * C_;
    float v[3], s = 0.f, sq = 0.f;
#pragma unroll
    for (int i = 0; i < 3; i++) {
        v[i] = xr[i * 256 + t];
        s += v[i]; sq += v[i] * v[i];
    }
    for (int m = 32; m; m >>= 1) { s += __shfl_xor(s, m); sq += __shfl_xor(sq, m); }
    __shared__ float ss[4], ssq[4];
    int wid = t >> 6;
    if ((t & 63) == 0) { ss[wid] = s; ssq[wid] = sq; }
    __syncthreads();
    s = ss[0] + ss[1] + ss[2] + ss[3];
    sq = ssq[0] + ssq[1] + ssq[2] + ssq[3];
    float mu = s * (1.f / C_);
    float var = sq * (1.f / C_) - mu * mu;
    float rstd = rsqrtf(var + 1e-5f);
#pragma unroll
    for (int i = 0; i < 3; i++) {
        int c = i * 256 + t;
        out[(size_t)row * C_ + c] = f2bf((v[i] - mu) * rstd * g[c] + b[c]);
    }
}

// ---------------- bf16 MFMA GEMM: out = A[M,K] @ W[N,K]^T (+bias, epilogues) ----------------
// EPI 0: outb = bf16(acc + bias)
// EPI 1: outb = bf16(gelu(acc + bias))          (exact gelu, erf)
// EPI 2: outf = res + ls * (acc + bias)
template <int EPI>
__global__ __launch_bounds__(256) void gemm_kernel(const u16* __restrict__ A,
                                                   const u16* __restrict__ W,
                                                   const float* __restrict__ bias,
                                                   float* __restrict__ outf,
                                                   u16* __restrict__ outb,
                                                   const float* __restrict__ res,
                                                   const float* __restrict__ ls,
                                                   int N, int K) {
    __shared__ u16 Alds[128 * 64];
    __shared__ u16 Blds[128 * 64];
    int tid = threadIdx.x;
    int m0 = blockIdx.y * 128, n0 = blockIdx.x * 128;
    int lane = tid & 63, wid = tid >> 6;
    int wr = wid >> 1, wc = wid & 1;
    int lr = lane & 15, lq = lane >> 4;

    f32x4 acc[4][4];
#pragma unroll
    for (int i = 0; i < 4; i++)
#pragma unroll
        for (int j = 0; j < 4; j++) acc[i][j] = (f32x4){0.f, 0.f, 0.f, 0.f};

    int nk = K >> 6;
    const u16* Ab = A + (size_t)m0 * K;
    const u16* Wb = W + (size_t)n0 * K;
    bf16x8 ra[4], rb[4];
#pragma unroll
    for (int i = 0; i < 4; i++) {
        int c = tid + i * 256, row = c >> 3, j = c & 7;
        ra[i] = *(const bf16x8*)(Ab + (size_t)row * K + j * 8);
        rb[i] = *(const bf16x8*)(Wb + (size_t)row * K + j * 8);
    }
    for (int kt = 0; kt < nk; ++kt) {
        __syncthreads();
#pragma unroll
        for (int i = 0; i < 4; i++) {
            int c = tid + i * 256, row = c >> 3, j = c & 7;
            int off = row * 64 + ((j ^ (row & 7)) << 3);   // XOR-swizzled 16B blocks
            *(bf16x8*)(Alds + off) = ra[i];
            *(bf16x8*)(Blds + off) = rb[i];
        }
        __syncthreads();
        if (kt + 1 < nk) {
            int k0 = (kt + 1) << 6;
#pragma unroll
            for (int i = 0; i < 4; i++) {
                int c = tid + i * 256, row = c >> 3, j = c & 7;
                ra[i] = *(const bf16x8*)(Ab + (size_t)row * K + k0 + j * 8);
                rb[i] = *(const bf16x8*)(Wb + (size_t)row * K + k0 + j * 8);
            }
        }
#pragma unroll
        for (int s = 0; s < 2; s++) {
            bf16x8 af[4], bw[4];
#pragma unroll
            for (int i = 0; i < 4; i++) {
                int arow = wr * 64 + i * 16 + lr;
                af[i] = *(const bf16x8*)(Alds + arow * 64 + (((4 * s + lq) ^ (arow & 7)) << 3));
                int brow = wc * 64 + i * 16 + lr;
                bw[i] = *(const bf16x8*)(Blds + brow * 64 + (((4 * s + lq) ^ (brow & 7)) << 3));
            }
#pragma unroll
            for (int i = 0; i < 4; i++)
#pragma unroll
                for (int j = 0; j < 4; j++)
                    acc[i][j] = __builtin_amdgcn_mfma_f32_16x16x32_bf16(af[i], bw[j], acc[i][j], 0, 0, 0);
        }
    }
#pragma unroll
    for (int i = 0; i < 4; i++) {
#pragma unroll
        for (int j = 0; j < 4; j++) {
#pragma unroll
            for (int r = 0; r < 4; r++) {
                int gm = m0 + wr * 64 + i * 16 + lq * 4 + r;
                int gn = n0 + wc * 64 + j * 16 + lr;
                float val = acc[i][j][r] + bias[gn];
                if (EPI == 0) {
                    outb[(size_t)gm * N + gn] = f2bf(val);
                } else if (EPI == 1) {
                    float gl = 0.5f * val * (1.f + erff(val * 0.70710678118654752f));
                    outb[(size_t)gm * N + gn] = f2bf(gl);
                } else {
                    outf[(size_t)gm * N + gn] = res[(size_t)gm * N + gn] + ls[gn] * val;
                }
            }
        }
    }
}

// ---------------- V transpose: qkv_buf v-part -> Vt [B,H,D,T] ----------------
__global__ __launch_bounds__(256) void vtrans_kernel(const u16* __restrict__ qkv,
                                                     u16* __restrict__ vt) {
    __shared__ u16 tile[64 * 72];
    int t0 = blockIdx.x * 64, h = blockIdx.y, b = blockIdx.z;
    int tid = threadIdx.x;
#pragma unroll
    for (int i = 0; i < 2; i++) {
        int c = tid + i * 256, tr = c >> 3, j = c & 7;
        bf16x8 v = *(const bf16x8*)(qkv + (size_t)(b * T_ + t0 + tr) * N3C + 1536 + h * 64 + j * 8);
        *(bf16x8*)(tile + tr * 72 + j * 8) = v;
    }
    __syncthreads();
#pragma unroll
    for (int i = 0; i < 2; i++) {
        int c = tid + i * 256, d = c >> 3, tj = c & 7;
        bf16x8 o;
#pragma unroll
        for (int k = 0; k < 8; k++) o[k] = (short)tile[(tj * 8 + k) * 72 + d];
        *(bf16x8*)(vt + (size_t)((b * H_ + h) * 64 + d) * T_ + t0 + tj * 8) = o;
    }
}

// ---------------- fused attention: QK^T+bias+mask -> softmax -> attn out + PV ----------------
__global__ __launch_bounds__(256) void attn_kernel(const u16* __restrict__ qkv,
                                                   const u16* __restrict__ vt,
                                                   const float* __restrict__ bias,
                                                   const float* __restrict__ mask,
                                                   float* __restrict__ attn_out,
                                                   u16* __restrict__ ybuf) {
    __shared__ float S[16 * 2048];   // 128 KB; later reused in place as bf16 P
    __shared__ float rinv_lds[16];
    char* Sb = (char*)S;
    int qt = blockIdx.x, h = blockIdx.y, b = blockIdx.z;
    int tid = threadIdx.x, lane = tid & 63, wid = tid >> 6;
    int lr = lane & 15, lq = lane >> 4;
    int q0 = qt * 16;
    size_t bh = (size_t)(b * H_ + h);
    const float scale = 0.125f;

    // ---- phase A: S = QK^T*scale + bias + mask (cols split across waves) ----
    const u16* qp = qkv + (size_t)(b * T_ + q0 + lr) * N3C + h * 64;
    bf16x8 qa0 = *(const bf16x8*)(qp + lq * 8);
    bf16x8 qa1 = *(const bf16x8*)(qp + 32 + lq * 8);
#pragma unroll 4
    for (int ct = 0; ct < 32; ++ct) {
        int col = wid * 512 + ct * 16 + lr;
        const u16* kp = qkv + (size_t)(b * T_ + col) * N3C + 768 + h * 64;
        bf16x8 kf0 = *(const bf16x8*)(kp + lq * 8);
        bf16x8 kf1 = *(const bf16x8*)(kp + 32 + lq * 8);
        f32x4 a = (f32x4){0.f, 0.f, 0.f, 0.f};
        a = __builtin_amdgcn_mfma_f32_16x16x32_bf16(qa0, kf0, a, 0, 0, 0);
        a = __builtin_amdgcn_mfma_f32_16x16x32_bf16(qa1, kf1, a, 0, 0, 0);
#pragma unroll
        for (int r = 0; r < 4; r++) {
            int row = lq * 4 + r;
            float sv = a[r] * scale + bias[(bh * T_ + q0 + row) * T_ + col]
                                    + mask[((size_t)b * T_ + q0 + row) * T_ + col];
            *(float*)(Sb + ((((size_t)row * 2048 + col) << 2) ^ ((row & 7) << 4))) = sv;
        }
    }
    __syncthreads();

    // ---- phase B: per-row softmax; wave w owns rows 4w..4w+3 ----
#pragma unroll 1
    for (int rr = 0; rr < 4; ++rr) {
        int r = wid * 4 + rr;
        size_t rowbase = (size_t)r * 8192;
        int swz = (r & 7) << 4;
        float mx = -1e30f;
        for (int i = 0; i < 32; i++) {
            int c = lane + i * 64;
            mx = fmaxf(mx, *(float*)(Sb + ((rowbase + 4 * (size_t)c) ^ swz)));
        }
        for (int m = 32; m; m >>= 1) mx = fmaxf(mx, __shfl_xor(mx, m));
        float lsum = 0.f;
        for (int i = 0; i < 16; i++) {
            int c0 = i * 128 + 2 * lane;
            float2 sv = *(float2*)(Sb + ((rowbase + 4 * (size_t)c0) ^ swz));
            float e0 = __expf(sv.x - mx), e1 = __expf(sv.y - mx);
            lsum += e0 + e1;
            u32 pk = ((u32)f2bf(e1) << 16) | (u32)f2bf(e0);
            *(u32*)(Sb + ((rowbase + 2 * (size_t)c0) ^ swz)) = pk;   // in-place bf16 P
        }
        for (int m = 32; m; m >>= 1) lsum += __shfl_xor(lsum, m);
        float rinv = 1.f / lsum;
        if (lane == 0) rinv_lds[r] = rinv;
        float* ao = attn_out + (bh * T_ + q0 + r) * T_;
        for (int i = 0; i < 16; i++) {
            int c0 = i * 128 + 2 * lane;
            u32 pk = *(u32*)(Sb + ((rowbase + 2 * (size_t)c0) ^ swz));
            float2 o;
            o.x = __uint_as_float((pk & 0xffffu) << 16) * rinv;
            o.y = __uint_as_float(pk & 0xffff0000u) * rinv;
            *(float2*)(ao + c0) = o;
        }
    }
    __syncthreads();

    // ---- phase C: y = (P @ V) * rinv; wave w owns d-cols 16w..16w+15 ----
    f32x4 acc = (f32x4){0.f, 0.f, 0.f, 0.f};
    const u16* vtp = vt + (bh * 64 + wid * 16 + lr) * (size_t)T_;
#pragma unroll 4
    for (int ks = 0; ks < 64; ++ks) {
        int row = lr;
        bf16x8 pf = *(const bf16x8*)(Sb + (((size_t)row * 8192 + 64 * (size_t)ks + 16 * lq) ^ ((row & 7) << 4)));
        bf16x8 vf = *(const bf16x8*)(vtp + ks * 32 + lq * 8);
        acc = __builtin_amdgcn_mfma_f32_16x16x32_bf16(pf, vf, acc, 0, 0, 0);
    }
#pragma unroll
    for (int r = 0; r < 4; r++) {
        int row = lq * 4 + r;
        float y = acc[r] * rinv_lds[row];
        ybuf[(size_t)(b * T_ + q0 + row) * C_ + h * 64 + wid * 16 + lr] = f2bf(y);
    }
}

// ---------------- host ----------------
extern "C" void kernel_launch(void* const* d_in, const int* in_sizes, int n_in,
                              void* d_out, int out_size, void* d_ws, size_t ws_size,
                              hipStream_t stream) {
    const float* x = (const float*)d_in[0];
    const float* mask = (const float*)d_in[1];
    const float* bias = (const float*)d_in[2];
    const float* ln1g = (const float*)d_in[3];
    const float* ln1b = (const float*)d_in[4];
    const float* qkvw = (const float*)d_in[5];
    const float* qkvb = (const float*)d_in[6];
    const float* projw = (const float*)d_in[7];
    const float* projb = (const float*)d_in[8];
    const float* ls1 = (const float*)d_in[9];
    const float* ln2g = (const float*)d_in[10];
    const float* ln2b = (const float*)d_in[11];
    const float* w1 = (const float*)d_in[12];
    const float* b1 = (const float*)d_in[13];
    const float* w2 = (const float*)d_in[14];
    const float* b2 = (const float*)d_in[15];
    const float* ls2 = (const float*)d_in[16];

    char* ws = (char*)d_ws;
    size_t off = 0;
    u16* qkvw_b = (u16*)(ws + off); off += (size_t)N3C * C_ * 2;
    u16* projw_b = (u16*)(ws + off); off += (size_t)C_ * C_ * 2;
    u16* w1_b = (u16*)(ws + off); off += (size_t)HID_ * C_ * 2;
    u16* w2_b = (u16*)(ws + off); off += (size_t)C_ * HID_ * 2;
    u16* xn = (u16*)(ws + off); off += (size_t)NROW * C_ * 2;          // reused as hn after attn
    u16* qkvbuf = (u16*)(ws + off); off += (size_t)NROW * N3C * 2;     // } contiguous; reused as
    u16* vt = (u16*)(ws + off); off += (size_t)B_ * H_ * D_ * T_ * 2;  // } g [4096,3072] after attn
    u16* g = qkvbuf;
    u16* ybuf = (u16*)(ws + off); off += (size_t)NROW * C_ * 2;
    float* x1 = (float*)(ws + off); off += (size_t)NROW * C_ * 4;
    (void)ws_size; (void)n_in; (void)in_sizes; (void)out_size;

    float* outx = (float*)d_out;
    float* attn_out = outx + (size_t)NROW * C_;

    // weights -> bf16
    cvt_bf16_kernel<<<(N3C * C_ / 4 + 255) / 256, 256, 0, stream>>>(qkvw, qkvw_b, N3C * C_);
    cvt_bf16_kernel<<<(C_ * C_ / 4 + 255) / 256, 256, 0, stream>>>(projw, projw_b, C_ * C_);
    cvt_bf16_kernel<<<(HID_ * C_ / 4 + 255) / 256, 256, 0, stream>>>(w1, w1_b, HID_ * C_);
    cvt_bf16_kernel<<<(C_ * HID_ / 4 + 255) / 256, 256, 0, stream>>>(w2, w2_b, C_ * HID_);

    // LN1
    ln_kernel<<<NROW, 256, 0, stream>>>(x, ln1g, ln1b, xn);
    // QKV
    gemm_kernel<0><<<dim3(N3C / 128, NROW / 128), 256, 0, stream>>>(
        xn, qkvw_b, qkvb, nullptr, qkvbuf, nullptr, nullptr, N3C, C_);
    // V transpose
    vtrans_kernel<<<dim3(T_ / 64, H_, B_), 256, 0, stream>>>(qkvbuf, vt);
    // fused attention
    attn_kernel<<<dim3(T_ / 16, H_, B_), 256, 0, stream>>>(qkvbuf, vt, bias, mask, attn_out, ybuf);
    // proj + residual*ls1 -> x1
    gemm_kernel<2><<<dim3(C_ / 128, NROW / 128), 256, 0, stream>>>(
        ybuf, projw_b, projb, x1, nullptr, x, ls1, C_, C_);
    // LN2
    ln_kernel<<<NROW, 256, 0, stream>>>(x1, ln2g, ln2b, xn);
    // MLP1 + gelu
    gemm_kernel<1><<<dim3(HID_ / 128, NROW / 128), 256, 0, stream>>>(
        xn, w1_b, b1, nullptr, g, nullptr, nullptr, HID_, C_);
    // MLP2 + residual*ls2 -> out
    gemm_kernel<2><<<dim3(C_ / 128, NROW / 128), 256, 0, stream>>>(
        g, w2_b, b2, outx, nullptr, x1, ls2, C_, HID_);
}

// Round 2
// 519.858 us; speedup vs baseline: 1.1184x; 1.1184x over previous
//
#include <hip/hip_runtime.h>
#include <hip/hip_bf16.h>
#include <math.h>

#define B_ 2
#define T_ 2048
#define C_ 768
#define H_ 12
#define D_ 64
#define HID_ 3072
#define NROW 4096   // B*T
#define N3C 2304    // 3*C

typedef short bf16x8 __attribute__((ext_vector_type(8)));
typedef float f32x4 __attribute__((ext_vector_type(4)));
typedef unsigned short u16;
typedef unsigned int u32;

__device__ inline u16 f2bf(float f) {
    u32 u = __float_as_uint(f);
    u32 r = (u + 0x7fffu + ((u >> 16) & 1u)) >> 16;  // RNE
    return (u16)r;
}

// ---------------- weight / activation f32 -> bf16 convert ----------------
__global__ __launch_bounds__(256) void cvt_bf16_kernel(const float* __restrict__ s,
                                                       u16* __restrict__ d, int n) {
    int i = (blockIdx.x * 256 + threadIdx.x) * 4;
    if (i >= n) return;
    float4 v = *(const float4*)(s + i);
    ushort4 o;
    o.x = f2bf(v.x); o.y = f2bf(v.y); o.z = f2bf(v.z); o.w = f2bf(v.w);
    *(ushort4*)(d + i) = o;
}

// ---------------- LayerNorm (f32 in, bf16 out), one block per row ----------------
__global__ __launch_bounds__(256) void ln_kernel(const float* __restrict__ x,
                                                 const float* __restrict__ g,
                                                 const float* __restrict__ b,
                                                 u16* __restrict__ out) {
    int row = blockIdx.x, t = threadIdx.x;
    const float* xr = x + (size_t)row * C_;
    float v[3], s = 0.f, sq = 0.f;
#pragma unroll
    for (int i = 0; i < 3; i++) {
        v[i] = xr[i * 256 + t];
        s += v[i]; sq += v[i] * v[i];
    }
    for (int m = 32; m; m >>= 1) { s += __shfl_xor(s, m); sq += __shfl_xor(sq, m); }
    __shared__ float ss[4], ssq[4];
    int wid = t >> 6;
    if ((t & 63) == 0) { ss[wid] = s; ssq[wid] = sq; }
    __syncthreads();
    s = ss[0] + ss[1] + ss[2] + ss[3];
    sq = ssq[0] + ssq[1] + ssq[2] + ssq[3];
    float mu = s * (1.f / C_);
    float var = sq * (1.f / C_) - mu * mu;
    float rstd = rsqrtf(var + 1e-5f);
#pragma unroll
    for (int i = 0; i < 3; i++) {
        int c = i * 256 + t;
        out[(size_t)row * C_ + c] = f2bf((v[i] - mu) * rstd * g[c] + b[c]);
    }
}

// ---------------- bf16 MFMA GEMM: out = A[M,K] @ W[N,K]^T (+bias, epilogues) ----------------
// EPI 0: outb = bf16(acc + bias)
// EPI 1: outb = bf16(gelu(acc + bias))          (exact gelu, erf)
// EPI 2: outf = res + ls * (acc + bias)
template <int EPI>
__global__ __launch_bounds__(256) void gemm_kernel(const u16* __restrict__ A,
                                                   const u16* __restrict__ W,
                                                   const float* __restrict__ bias,
                                                   float* __restrict__ outf,
                                                   u16* __restrict__ outb,
                                                   const float* __restrict__ res,
                                                   const float* __restrict__ ls,
                                                   int N, int K) {
    __shared__ u16 Alds[128 * 64];
    __shared__ u16 Blds[128 * 64];
    int tid = threadIdx.x;
    int m0 = blockIdx.y * 128, n0 = blockIdx.x * 128;
    int lane = tid & 63, wid = tid >> 6;
    int wr = wid >> 1, wc = wid & 1;
    int lr = lane & 15, lq = lane >> 4;

    f32x4 acc[4][4];
#pragma unroll
    for (int i = 0; i < 4; i++)
#pragma unroll
        for (int j = 0; j < 4; j++) acc[i][j] = (f32x4){0.f, 0.f, 0.f, 0.f};

    int nk = K >> 6;
    const u16* Ab = A + (size_t)m0 * K;
    const u16* Wb = W + (size_t)n0 * K;
    bf16x8 ra[4], rb[4];
#pragma unroll
    for (int i = 0; i < 4; i++) {
        int c = tid + i * 256, row = c >> 3, j = c & 7;
        ra[i] = *(const bf16x8*)(Ab + (size_t)row * K + j * 8);
        rb[i] = *(const bf16x8*)(Wb + (size_t)row * K + j * 8);
    }
    for (int kt = 0; kt < nk; ++kt) {
        __syncthreads();
#pragma unroll
        for (int i = 0; i < 4; i++) {
            int c = tid + i * 256, row = c >> 3, j = c & 7;
            int off = row * 64 + ((j ^ (row & 7)) << 3);   // XOR-swizzled 16B blocks
            *(bf16x8*)(Alds + off) = ra[i];
            *(bf16x8*)(Blds + off) = rb[i];
        }
        __syncthreads();
        if (kt + 1 < nk) {
            int k0 = (kt + 1) << 6;
#pragma unroll
            for (int i = 0; i < 4; i++) {
                int c = tid + i * 256, row = c >> 3, j = c & 7;
                ra[i] = *(const bf16x8*)(Ab + (size_t)row * K + k0 + j * 8);
                rb[i] = *(const bf16x8*)(Wb + (size_t)row * K + k0 + j * 8);
            }
        }
#pragma unroll
        for (int s = 0; s < 2; s++) {
            bf16x8 af[4], bw[4];
#pragma unroll
            for (int i = 0; i < 4; i++) {
                int arow = wr * 64 + i * 16 + lr;
                af[i] = *(const bf16x8*)(Alds + arow * 64 + (((4 * s + lq) ^ (arow & 7)) << 3));
                int brow = wc * 64 + i * 16 + lr;
                bw[i] = *(const bf16x8*)(Blds + brow * 64 + (((4 * s + lq) ^ (brow & 7)) << 3));
            }
#pragma unroll
            for (int i = 0; i < 4; i++)
#pragma unroll
                for (int j = 0; j < 4; j++)
                    acc[i][j] = __builtin_amdgcn_mfma_f32_16x16x32_bf16(af[i], bw[j], acc[i][j], 0, 0, 0);
        }
    }
#pragma unroll
    for (int i = 0; i < 4; i++) {
#pragma unroll
        for (int j = 0; j < 4; j++) {
#pragma unroll
            for (int r = 0; r < 4; r++) {
                int gm = m0 + wr * 64 + i * 16 + lq * 4 + r;
                int gn = n0 + wc * 64 + j * 16 + lr;
                float val = acc[i][j][r] + bias[gn];
                if (EPI == 0) {
                    outb[(size_t)gm * N + gn] = f2bf(val);
                } else if (EPI == 1) {
                    float gl = 0.5f * val * (1.f + erff(val * 0.70710678118654752f));
                    outb[(size_t)gm * N + gn] = f2bf(gl);
                } else {
                    outf[(size_t)gm * N + gn] = res[(size_t)gm * N + gn] + ls[gn] * val;
                }
            }
        }
    }
}

// ---------------- V transpose: qkv_buf v-part -> Vt [B,H,D,T] ----------------
__global__ __launch_bounds__(256) void vtrans_kernel(const u16* __restrict__ qkv,
                                                     u16* __restrict__ vt) {
    __shared__ u16 tile[64 * 72];
    int t0 = blockIdx.x * 64, h = blockIdx.y, b = blockIdx.z;
    int tid = threadIdx.x;
#pragma unroll
    for (int i = 0; i < 2; i++) {
        int c = tid + i * 256, tr = c >> 3, j = c & 7;
        bf16x8 v = *(const bf16x8*)(qkv + (size_t)(b * T_ + t0 + tr) * N3C + 1536 + h * 64 + j * 8);
        *(bf16x8*)(tile + tr * 72 + j * 8) = v;
    }
    __syncthreads();
#pragma unroll
    for (int i = 0; i < 2; i++) {
        int c = tid + i * 256, d = c >> 3, tj = c & 7;
        bf16x8 o;
#pragma unroll
        for (int k = 0; k < 8; k++) o[k] = (short)tile[(tj * 8 + k) * 72 + d];
        *(bf16x8*)(vt + (size_t)((b * H_ + h) * 64 + d) * T_ + t0 + tj * 8) = o;
    }
}

// ---------------- fused attention ----------------
// S stored bf16 in LDS (64 KB -> 2 blocks/CU). Swapped mfma(K,Q): each lane
// holds 4 consecutive S-cols of one S-row -> ds_write_b64 store (conflict-free)
// and float4 bias/mask loads (fully coalesced).
__global__ __launch_bounds__(256, 2) void attn_kernel(const u16* __restrict__ qkv,
                                                      const u16* __restrict__ vt,
                                                      const float* __restrict__ bias,
                                                      const float* __restrict__ mask,
                                                      float* __restrict__ attn_out,
                                                      u16* __restrict__ ybuf) {
    __shared__ u16 S[16 * 2048];     // bf16 logits, then bf16 P in place
    __shared__ float rinv_lds[16];
    char* Sb = (char*)S;
    int qt = blockIdx.x, h = blockIdx.y, b = blockIdx.z;
    int tid = threadIdx.x, lane = tid & 63, wid = tid >> 6;
    int lr = lane & 15, lq = lane >> 4;
    int q0 = qt * 16;
    size_t bh = (size_t)(b * H_ + h);
    const float scale = 0.125f;

    // ---- phase A: S[qq][kk] = bf16(QK^T*scale + bias + mask) ----
    const u16* qp = qkv + (size_t)(b * T_ + q0 + lr) * N3C + h * 64;
    bf16x8 qa0 = *(const bf16x8*)(qp + lq * 8);
    bf16x8 qa1 = *(const bf16x8*)(qp + 32 + lq * 8);
    const float* bp = bias + (bh * T_ + q0 + lr) * T_;
    const float* mp = mask + ((size_t)b * T_ + q0 + lr) * T_;
#pragma unroll 4
    for (int ct = 0; ct < 32; ++ct) {
        int colbase = wid * 512 + ct * 16;
        const u16* kp = qkv + (size_t)(b * T_ + colbase + lr) * N3C + 768 + h * 64;
        bf16x8 kf0 = *(const bf16x8*)(kp + lq * 8);
        bf16x8 kf1 = *(const bf16x8*)(kp + 32 + lq * 8);
        float4 b4 = *(const float4*)(bp + colbase + lq * 4);
        float4 m4 = *(const float4*)(mp + colbase + lq * 4);
        f32x4 a = (f32x4){0.f, 0.f, 0.f, 0.f};
        a = __builtin_amdgcn_mfma_f32_16x16x32_bf16(kf0, qa0, a, 0, 0, 0);
        a = __builtin_amdgcn_mfma_f32_16x16x32_bf16(kf1, qa1, a, 0, 0, 0);
        // lane holds S[row=lr][cols colbase+lq*4 .. +3]
        ushort4 pk;
        pk.x = f2bf(a[0] * scale + b4.x + m4.x);
        pk.y = f2bf(a[1] * scale + b4.y + m4.y);
        pk.z = f2bf(a[2] * scale + b4.z + m4.z);
        pk.w = f2bf(a[3] * scale + b4.w + m4.w);
        *(ushort4*)(Sb + (((u32)lr * 4096 + 2 * colbase + 8 * lq) ^ ((lr & 7) << 4))) = pk;
    }
    __syncthreads();

    // ---- phase B: per-row softmax; wave w owns rows 4w..4w+3 ----
    float* ao_base = attn_out + (bh * T_ + q0) * T_;
#pragma unroll 1
    for (int rr = 0; rr < 4; ++rr) {
        int r = wid * 4 + rr;
        u32 rowb = (u32)r * 4096;
        int swz = (r & 7) << 4;
        u32 pk[16];
        float mx = -1e30f;
#pragma unroll
        for (int i = 0; i < 16; i++) {
            pk[i] = *(u32*)(Sb + ((rowb + i * 256 + 4 * lane) ^ swz));
            float lo = __uint_as_float(pk[i] << 16);
            float hi = __uint_as_float(pk[i] & 0xffff0000u);
            mx = fmaxf(mx, fmaxf(lo, hi));
        }
        for (int m = 32; m; m >>= 1) mx = fmaxf(mx, __shfl_xor(mx, m));
        float e[32];
        float lsum = 0.f;
#pragma unroll
        for (int i = 0; i < 16; i++) {
            float lo = __uint_as_float(pk[i] << 16);
            float hi = __uint_as_float(pk[i] & 0xffff0000u);
            float e0 = __expf(lo - mx), e1 = __expf(hi - mx);
            e[2 * i] = e0; e[2 * i + 1] = e1;
            lsum += e0 + e1;
            u32 po = ((u32)f2bf(e1) << 16) | (u32)f2bf(e0);
            *(u32*)(Sb + ((rowb + i * 256 + 4 * lane) ^ swz)) = po;  // in-place bf16 P
        }
        for (int m = 32; m; m >>= 1) lsum += __shfl_xor(lsum, m);
        float rinv = 1.f / lsum;
        if (lane == 0) rinv_lds[r] = rinv;
        float* ao = ao_base + (size_t)r * T_;
#pragma unroll
        for (int i = 0; i < 16; i++) {
            float2 o;
            o.x = e[2 * i] * rinv;
            o.y = e[2 * i + 1] * rinv;
            *(float2*)(ao + i * 128 + 2 * lane) = o;
        }
    }
    __syncthreads();

    // ---- phase C: y = (P @ V) * rinv; wave w owns d-cols 16w..16w+15 ----
    f32x4 acc = (f32x4){0.f, 0.f, 0.f, 0.f};
    const u16* vtp = vt + (bh * 64 + wid * 16 + lr) * (size_t)T_;
#pragma unroll 4
    for (int ks = 0; ks < 64; ++ks) {
        bf16x8 pf = *(const bf16x8*)(Sb + (((u32)lr * 4096 + ks * 64 + lq * 16) ^ ((lr & 7) << 4)));
        bf16x8 vf = *(const bf16x8*)(vtp + ks * 32 + lq * 8);
        acc = __builtin_amdgcn_mfma_f32_16x16x32_bf16(pf, vf, acc, 0, 0, 0);
    }
#pragma unroll
    for (int r = 0; r < 4; r++) {
        int row = lq * 4 + r;
        float y = acc[r] * rinv_lds[row];
        ybuf[(size_t)(b * T_ + q0 + row) * C_ + h * 64 + wid * 16 + lr] = f2bf(y);
    }
}

// ---------------- host ----------------
extern "C" void kernel_launch(void* const* d_in, const int* in_sizes, int n_in,
                              void* d_out, int out_size, void* d_ws, size_t ws_size,
                              hipStream_t stream) {
    const float* x = (const float*)d_in[0];
    const float* mask = (const float*)d_in[1];
    const float* bias = (const float*)d_in[2];
    const float* ln1g = (const float*)d_in[3];
    const float* ln1b = (const float*)d_in[4];
    const float* qkvw = (const float*)d_in[5];
    const float* qkvb = (const float*)d_in[6];
    const float* projw = (const float*)d_in[7];
    const float* projb = (const float*)d_in[8];
    const float* ls1 = (const float*)d_in[9];
    const float* ln2g = (const float*)d_in[10];
    const float* ln2b = (const float*)d_in[11];
    const float* w1 = (const float*)d_in[12];
    const float* b1 = (const float*)d_in[13];
    const float* w2 = (const float*)d_in[14];
    const float* b2 = (const float*)d_in[15];
    const float* ls2 = (const float*)d_in[16];

    char* ws = (char*)d_ws;
    size_t off = 0;
    u16* qkvw_b = (u16*)(ws + off); off += (size_t)N3C * C_ * 2;
    u16* projw_b = (u16*)(ws + off); off += (size_t)C_ * C_ * 2;
    u16* w1_b = (u16*)(ws + off); off += (size_t)HID_ * C_ * 2;
    u16* w2_b = (u16*)(ws + off); off += (size_t)C_ * HID_ * 2;
    u16* xn = (u16*)(ws + off); off += (size_t)NROW * C_ * 2;          // reused as hn after attn
    u16* qkvbuf = (u16*)(ws + off); off += (size_t)NROW * N3C * 2;     // } contiguous; reused as
    u16* vt = (u16*)(ws + off); off += (size_t)B_ * H_ * D_ * T_ * 2;  // } g [4096,3072] after attn
    u16* g = qkvbuf;
    u16* ybuf = (u16*)(ws + off); off += (size_t)NROW * C_ * 2;
    float* x1 = (float*)(ws + off); off += (size_t)NROW * C_ * 4;
    (void)ws_size; (void)n_in; (void)in_sizes; (void)out_size;

    float* outx = (float*)d_out;
    float* attn_out = outx + (size_t)NROW * C_;

    // weights -> bf16
    cvt_bf16_kernel<<<(N3C * C_ / 4 + 255) / 256, 256, 0, stream>>>(qkvw, qkvw_b, N3C * C_);
    cvt_bf16_kernel<<<(C_ * C_ / 4 + 255) / 256, 256, 0, stream>>>(projw, projw_b, C_ * C_);
    cvt_bf16_kernel<<<(HID_ * C_ / 4 + 255) / 256, 256, 0, stream>>>(w1, w1_b, HID_ * C_);
    cvt_bf16_kernel<<<(C_ * HID_ / 4 + 255) / 256, 256, 0, stream>>>(w2, w2_b, C_ * HID_);

    // LN1
    ln_kernel<<<NROW, 256, 0, stream>>>(x, ln1g, ln1b, xn);
    // QKV
    gemm_kernel<0><<<dim3(N3C / 128, NROW / 128), 256, 0, stream>>>(
        xn, qkvw_b, qkvb, nullptr, qkvbuf, nullptr, nullptr, N3C, C_);
    // V transpose
    vtrans_kernel<<<dim3(T_ / 64, H_, B_), 256, 0, stream>>>(qkvbuf, vt);
    // fused attention
    attn_kernel<<<dim3(T_ / 16, H_, B_), 256, 0, stream>>>(qkvbuf, vt, bias, mask, attn_out, ybuf);
    // proj + residual*ls1 -> x1
    gemm_kernel<2><<<dim3(C_ / 128, NROW / 128), 256, 0, stream>>>(
        ybuf, projw_b, projb, x1, nullptr, x, ls1, C_, C_);
    // LN2
    ln_kernel<<<NROW, 256, 0, stream>>>(x1, ln2g, ln2b, xn);
    // MLP1 + gelu
    gemm_kernel<1><<<dim3(HID_ / 128, NROW / 128), 256, 0, stream>>>(
        xn, w1_b, b1, nullptr, g, nullptr, nullptr, HID_, C_);
    // MLP2 + residual*ls2 -> out
    gemm_kernel<2><<<dim3(C_ / 128, NROW / 128), 256, 0, stream>>>(
        g, w2_b, b2, outx, nullptr, x1, ls2, C_, HID_);
}

// Round 3
// 514.014 us; speedup vs baseline: 1.1311x; 1.0114x over previous
//
#include <hip/hip_runtime.h>
#include <hip/hip_bf16.h>
#include <math.h>

#define B_ 2
#define T_ 2048
#define C_ 768
#define H_ 12
#define D_ 64
#define HID_ 3072
#define NROW 4096   // B*T
#define N3C 2304    // 3*C

typedef short bf16x8 __attribute__((ext_vector_type(8)));
typedef float f32x4 __attribute__((ext_vector_type(4)));
typedef unsigned short u16;
typedef unsigned int u32;

__device__ inline u16 f2bf(float f) {
    u32 u = __float_as_uint(f);
    u32 r = (u + 0x7fffu + ((u >> 16) & 1u)) >> 16;  // RNE
    return (u16)r;
}

// ---------------- weight / activation f32 -> bf16 convert ----------------
__global__ __launch_bounds__(256) void cvt_bf16_kernel(const float* __restrict__ s,
                                                       u16* __restrict__ d, int n) {
    int i = (blockIdx.x * 256 + threadIdx.x) * 4;
    if (i >= n) return;
    float4 v = *(const float4*)(s + i);
    ushort4 o;
    o.x = f2bf(v.x); o.y = f2bf(v.y); o.z = f2bf(v.z); o.w = f2bf(v.w);
    *(ushort4*)(d + i) = o;
}

// ---------------- LayerNorm (f32 in, bf16 out), one block per row ----------------
__global__ __launch_bounds__(256) void ln_kernel(const float* __restrict__ x,
                                                 const float* __restrict__ g,
                                                 const float* __restrict__ b,
                                                 u16* __restrict__ out) {
    int row = blockIdx.x, t = threadIdx.x;
    const float* xr = x + (size_t)row * C_;
    float v[3], s = 0.f, sq = 0.f;
#pragma unroll
    for (int i = 0; i < 3; i++) {
        v[i] = xr[i * 256 + t];
        s += v[i]; sq += v[i] * v[i];
    }
    for (int m = 32; m; m >>= 1) { s += __shfl_xor(s, m); sq += __shfl_xor(sq, m); }
    __shared__ float ss[4], ssq[4];
    int wid = t >> 6;
    if ((t & 63) == 0) { ss[wid] = s; ssq[wid] = sq; }
    __syncthreads();
    s = ss[0] + ss[1] + ss[2] + ss[3];
    sq = ssq[0] + ssq[1] + ssq[2] + ssq[3];
    float mu = s * (1.f / C_);
    float var = sq * (1.f / C_) - mu * mu;
    float rstd = rsqrtf(var + 1e-5f);
#pragma unroll
    for (int i = 0; i < 3; i++) {
        int c = i * 256 + t;
        out[(size_t)row * C_ + c] = f2bf((v[i] - mu) * rstd * g[c] + b[c]);
    }
}

// ---------------- bf16 MFMA GEMM: out = A[M,K] @ W[N,K]^T (+bias, epilogues) ----------------
// EPI 0: outb = bf16(acc + bias)
// EPI 1: outb = bf16(gelu(acc + bias))          (exact gelu, erf)
// EPI 2: outf = res + ls * (acc + bias)
template <int EPI>
__global__ __launch_bounds__(256) void gemm_kernel(const u16* __restrict__ A,
                                                   const u16* __restrict__ W,
                                                   const float* __restrict__ bias,
                                                   float* __restrict__ outf,
                                                   u16* __restrict__ outb,
                                                   const float* __restrict__ res,
                                                   const float* __restrict__ ls,
                                                   int N, int K) {
    __shared__ u16 Alds[128 * 64];
    __shared__ u16 Blds[128 * 64];
    int tid = threadIdx.x;
    int m0 = blockIdx.y * 128, n0 = blockIdx.x * 128;
    int lane = tid & 63, wid = tid >> 6;
    int wr = wid >> 1, wc = wid & 1;
    int lr = lane & 15, lq = lane >> 4;

    f32x4 acc[4][4];
#pragma unroll
    for (int i = 0; i < 4; i++)
#pragma unroll
        for (int j = 0; j < 4; j++) acc[i][j] = (f32x4){0.f, 0.f, 0.f, 0.f};

    int nk = K >> 6;
    const u16* Ab = A + (size_t)m0 * K;
    const u16* Wb = W + (size_t)n0 * K;
    bf16x8 ra[4], rb[4];
#pragma unroll
    for (int i = 0; i < 4; i++) {
        int c = tid + i * 256, row = c >> 3, j = c & 7;
        ra[i] = *(const bf16x8*)(Ab + (size_t)row * K + j * 8);
        rb[i] = *(const bf16x8*)(Wb + (size_t)row * K + j * 8);
    }
    for (int kt = 0; kt < nk; ++kt) {
        __syncthreads();
#pragma unroll
        for (int i = 0; i < 4; i++) {
            int c = tid + i * 256, row = c >> 3, j = c & 7;
            int off = row * 64 + ((j ^ (row & 7)) << 3);   // XOR-swizzled 16B blocks
            *(bf16x8*)(Alds + off) = ra[i];
            *(bf16x8*)(Blds + off) = rb[i];
        }
        __syncthreads();
        if (kt + 1 < nk) {
            int k0 = (kt + 1) << 6;
#pragma unroll
            for (int i = 0; i < 4; i++) {
                int c = tid + i * 256, row = c >> 3, j = c & 7;
                ra[i] = *(const bf16x8*)(Ab + (size_t)row * K + k0 + j * 8);
                rb[i] = *(const bf16x8*)(Wb + (size_t)row * K + k0 + j * 8);
            }
        }
#pragma unroll
        for (int s = 0; s < 2; s++) {
            bf16x8 af[4], bw[4];
#pragma unroll
            for (int i = 0; i < 4; i++) {
                int arow = wr * 64 + i * 16 + lr;
                af[i] = *(const bf16x8*)(Alds + arow * 64 + (((4 * s + lq) ^ (arow & 7)) << 3));
                int brow = wc * 64 + i * 16 + lr;
                bw[i] = *(const bf16x8*)(Blds + brow * 64 + (((4 * s + lq) ^ (brow & 7)) << 3));
            }
#pragma unroll
            for (int i = 0; i < 4; i++)
#pragma unroll
                for (int j = 0; j < 4; j++)
                    acc[i][j] = __builtin_amdgcn_mfma_f32_16x16x32_bf16(af[i], bw[j], acc[i][j], 0, 0, 0);
        }
    }
#pragma unroll
    for (int i = 0; i < 4; i++) {
#pragma unroll
        for (int j = 0; j < 4; j++) {
#pragma unroll
            for (int r = 0; r < 4; r++) {
                int gm = m0 + wr * 64 + i * 16 + lq * 4 + r;
                int gn = n0 + wc * 64 + j * 16 + lr;
                float val = acc[i][j][r] + bias[gn];
                if (EPI == 0) {
                    outb[(size_t)gm * N + gn] = f2bf(val);
                } else if (EPI == 1) {
                    float gl = 0.5f * val * (1.f + erff(val * 0.70710678118654752f));
                    outb[(size_t)gm * N + gn] = f2bf(gl);
                } else {
                    outf[(size_t)gm * N + gn] = res[(size_t)gm * N + gn] + ls[gn] * val;
                }
            }
        }
    }
}

// ---------------- V transpose: qkv_buf v-part -> Vt [B,H,D,T] ----------------
__global__ __launch_bounds__(256) void vtrans_kernel(const u16* __restrict__ qkv,
                                                     u16* __restrict__ vt) {
    __shared__ u16 tile[64 * 72];
    int t0 = blockIdx.x * 64, h = blockIdx.y, b = blockIdx.z;
    int tid = threadIdx.x;
#pragma unroll
    for (int i = 0; i < 2; i++) {
        int c = tid + i * 256, tr = c >> 3, j = c & 7;
        bf16x8 v = *(const bf16x8*)(qkv + (size_t)(b * T_ + t0 + tr) * N3C + 1536 + h * 64 + j * 8);
        *(bf16x8*)(tile + tr * 72 + j * 8) = v;
    }
    __syncthreads();
#pragma unroll
    for (int i = 0; i < 2; i++) {
        int c = tid + i * 256, d = c >> 3, tj = c & 7;
        bf16x8 o;
#pragma unroll
        for (int k = 0; k < 8; k++) o[k] = (short)tile[(tj * 8 + k) * 72 + d];
        *(bf16x8*)(vt + (size_t)((b * H_ + h) * 64 + d) * T_ + t0 + tj * 8) = o;
    }
}

// ---------------- fused attention ----------------
// S stored bf16 in LDS (64 KB -> 2 blocks/CU). Swapped mfma(K,Q): lane holds
// S[row=lr][4 consecutive cols]. Deep register prefetch (bias/mask depth-8,
// K depth-4, V depth-8) keeps ~16 HBM loads in flight per lane to cover
// ~900-cycle latency -- the R1->R2 lesson: occupancy alone didn't fix BW.
__global__ __launch_bounds__(256, 2) void attn_kernel(const u16* __restrict__ qkv,
                                                      const u16* __restrict__ vt,
                                                      const float* __restrict__ bias,
                                                      const float* __restrict__ mask,
                                                      float* __restrict__ attn_out,
                                                      u16* __restrict__ ybuf) {
    __shared__ u16 S[16 * 2048];     // bf16 logits, then bf16 P in place
    __shared__ float rinv_lds[16];
    char* Sb = (char*)S;
    int qt = blockIdx.x, h = blockIdx.y, b = blockIdx.z;
    int tid = threadIdx.x, lane = tid & 63, wid = tid >> 6;
    int lr = lane & 15, lq = lane >> 4;
    int q0 = qt * 16;
    size_t bh = (size_t)(b * H_ + h);
    const float scale = 0.125f;

    // ---- phase A: S[qq][kk] = bf16(QK^T*scale + bias + mask) ----
    const u16* qp = qkv + (size_t)(b * T_ + q0 + lr) * N3C + h * 64;
    bf16x8 qa0 = *(const bf16x8*)(qp + lq * 8);
    bf16x8 qa1 = *(const bf16x8*)(qp + 32 + lq * 8);
    const float* bp = bias + (bh * T_ + q0 + lr) * T_ + wid * 512 + lq * 4;
    const float* mp = mask + ((size_t)b * T_ + q0 + lr) * T_ + wid * 512 + lq * 4;
    const u16* kbase = qkv + (size_t)(b * T_ + wid * 512 + lr) * N3C + 768 + h * 64 + lq * 8;

    float4 bbuf[8], mbuf[8];
    bf16x8 k0buf[4], k1buf[4];
#pragma unroll
    for (int i = 0; i < 8; i++) {
        bbuf[i] = *(const float4*)(bp + i * 16);
        mbuf[i] = *(const float4*)(mp + i * 16);
    }
#pragma unroll
    for (int i = 0; i < 4; i++) {
        k0buf[i] = *(const bf16x8*)(kbase + (size_t)i * 16 * N3C);
        k1buf[i] = *(const bf16x8*)(kbase + (size_t)i * 16 * N3C + 32);
    }
#pragma unroll
    for (int ct = 0; ct < 32; ++ct) {
        bf16x8 kf0 = k0buf[ct & 3], kf1 = k1buf[ct & 3];
        float4 b4 = bbuf[ct & 7], m4 = mbuf[ct & 7];
        if (ct + 4 < 32) {
            k0buf[ct & 3] = *(const bf16x8*)(kbase + (size_t)(ct + 4) * 16 * N3C);
            k1buf[ct & 3] = *(const bf16x8*)(kbase + (size_t)(ct + 4) * 16 * N3C + 32);
        }
        if (ct + 8 < 32) {
            bbuf[ct & 7] = *(const float4*)(bp + (ct + 8) * 16);
            mbuf[ct & 7] = *(const float4*)(mp + (ct + 8) * 16);
        }
        f32x4 a = (f32x4){0.f, 0.f, 0.f, 0.f};
        a = __builtin_amdgcn_mfma_f32_16x16x32_bf16(kf0, qa0, a, 0, 0, 0);
        a = __builtin_amdgcn_mfma_f32_16x16x32_bf16(kf1, qa1, a, 0, 0, 0);
        // lane holds S[row=lr][cols colbase+lq*4 .. +3]
        int colbase = wid * 512 + ct * 16;
        ushort4 pk;
        pk.x = f2bf(a[0] * scale + b4.x + m4.x);
        pk.y = f2bf(a[1] * scale + b4.y + m4.y);
        pk.z = f2bf(a[2] * scale + b4.z + m4.z);
        pk.w = f2bf(a[3] * scale + b4.w + m4.w);
        *(ushort4*)(Sb + (((u32)lr * 4096 + 2 * colbase + 8 * lq) ^ ((lr & 7) << 4))) = pk;
    }
    __syncthreads();

    // ---- phase B: per-row softmax; wave w owns rows 4w..4w+3 ----
    float* ao_base = attn_out + (bh * T_ + q0) * T_;
#pragma unroll 1
    for (int rr = 0; rr < 4; ++rr) {
        int r = wid * 4 + rr;
        u32 rowb = (u32)r * 4096;
        int swz = (r & 7) << 4;
        u32 pk[16];
        float mx = -1e30f;
#pragma unroll
        for (int i = 0; i < 16; i++) {
            pk[i] = *(u32*)(Sb + ((rowb + i * 256 + 4 * lane) ^ swz));
            float lo = __uint_as_float(pk[i] << 16);
            float hi = __uint_as_float(pk[i] & 0xffff0000u);
            mx = fmaxf(mx, fmaxf(lo, hi));
        }
        for (int m = 32; m; m >>= 1) mx = fmaxf(mx, __shfl_xor(mx, m));
        float e[32];
        float lsum = 0.f;
#pragma unroll
        for (int i = 0; i < 16; i++) {
            float lo = __uint_as_float(pk[i] << 16);
            float hi = __uint_as_float(pk[i] & 0xffff0000u);
            float e0 = __expf(lo - mx), e1 = __expf(hi - mx);
            e[2 * i] = e0; e[2 * i + 1] = e1;
            lsum += e0 + e1;
            u32 po = ((u32)f2bf(e1) << 16) | (u32)f2bf(e0);
            *(u32*)(Sb + ((rowb + i * 256 + 4 * lane) ^ swz)) = po;  // in-place bf16 P
        }
        for (int m = 32; m; m >>= 1) lsum += __shfl_xor(lsum, m);
        float rinv = 1.f / lsum;
        if (lane == 0) rinv_lds[r] = rinv;
        float* ao = ao_base + (size_t)r * T_;
#pragma unroll
        for (int i = 0; i < 16; i++) {
            float2 o;
            o.x = e[2 * i] * rinv;
            o.y = e[2 * i + 1] * rinv;
            *(float2*)(ao + i * 128 + 2 * lane) = o;
        }
    }
    __syncthreads();

    // ---- phase C: y = (P @ V) * rinv; wave w owns d-cols 16w..16w+15 ----
    f32x4 acc = (f32x4){0.f, 0.f, 0.f, 0.f};
    const u16* vtp = vt + (bh * 64 + wid * 16 + lr) * (size_t)T_ + lq * 8;
    bf16x8 vbuf[8];
#pragma unroll
    for (int i = 0; i < 8; i++) vbuf[i] = *(const bf16x8*)(vtp + i * 32);
#pragma unroll
    for (int ks = 0; ks < 64; ++ks) {
        bf16x8 vf = vbuf[ks & 7];
        if (ks + 8 < 64) vbuf[ks & 7] = *(const bf16x8*)(vtp + (ks + 8) * 32);
        bf16x8 pf = *(const bf16x8*)(Sb + (((u32)lr * 4096 + ks * 64 + lq * 16) ^ ((lr & 7) << 4)));
        acc = __builtin_amdgcn_mfma_f32_16x16x32_bf16(pf, vf, acc, 0, 0, 0);
    }
#pragma unroll
    for (int r = 0; r < 4; r++) {
        int row = lq * 4 + r;
        float y = acc[r] * rinv_lds[row];
        ybuf[(size_t)(b * T_ + q0 + row) * C_ + h * 64 + wid * 16 + lr] = f2bf(y);
    }
}

// ---------------- host ----------------
extern "C" void kernel_launch(void* const* d_in, const int* in_sizes, int n_in,
                              void* d_out, int out_size, void* d_ws, size_t ws_size,
                              hipStream_t stream) {
    const float* x = (const float*)d_in[0];
    const float* mask = (const float*)d_in[1];
    const float* bias = (const float*)d_in[2];
    const float* ln1g = (const float*)d_in[3];
    const float* ln1b = (const float*)d_in[4];
    const float* qkvw = (const float*)d_in[5];
    const float* qkvb = (const float*)d_in[6];
    const float* projw = (const float*)d_in[7];
    const float* projb = (const float*)d_in[8];
    const float* ls1 = (const float*)d_in[9];
    const float* ln2g = (const float*)d_in[10];
    const float* ln2b = (const float*)d_in[11];
    const float* w1 = (const float*)d_in[12];
    const float* b1 = (const float*)d_in[13];
    const float* w2 = (const float*)d_in[14];
    const float* b2 = (const float*)d_in[15];
    const float* ls2 = (const float*)d_in[16];

    char* ws = (char*)d_ws;
    size_t off = 0;
    u16* qkvw_b = (u16*)(ws + off); off += (size_t)N3C * C_ * 2;
    u16* projw_b = (u16*)(ws + off); off += (size_t)C_ * C_ * 2;
    u16* w1_b = (u16*)(ws + off); off += (size_t)HID_ * C_ * 2;
    u16* w2_b = (u16*)(ws + off); off += (size_t)C_ * HID_ * 2;
    u16* xn = (u16*)(ws + off); off += (size_t)NROW * C_ * 2;          // reused as hn after attn
    u16* qkvbuf = (u16*)(ws + off); off += (size_t)NROW * N3C * 2;     // } contiguous; reused as
    u16* vt = (u16*)(ws + off); off += (size_t)B_ * H_ * D_ * T_ * 2;  // } g [4096,3072] after attn
    u16* g = qkvbuf;
    u16* ybuf = (u16*)(ws + off); off += (size_t)NROW * C_ * 2;
    float* x1 = (float*)(ws + off); off += (size_t)NROW * C_ * 4;
    (void)ws_size; (void)n_in; (void)in_sizes; (void)out_size;

    float* outx = (float*)d_out;
    float* attn_out = outx + (size_t)NROW * C_;

    // weights -> bf16
    cvt_bf16_kernel<<<(N3C * C_ / 4 + 255) / 256, 256, 0, stream>>>(qkvw, qkvw_b, N3C * C_);
    cvt_bf16_kernel<<<(C_ * C_ / 4 + 255) / 256, 256, 0, stream>>>(projw, projw_b, C_ * C_);
    cvt_bf16_kernel<<<(HID_ * C_ / 4 + 255) / 256, 256, 0, stream>>>(w1, w1_b, HID_ * C_);
    cvt_bf16_kernel<<<(C_ * HID_ / 4 + 255) / 256, 256, 0, stream>>>(w2, w2_b, C_ * HID_);

    // LN1
    ln_kernel<<<NROW, 256, 0, stream>>>(x, ln1g, ln1b, xn);
    // QKV
    gemm_kernel<0><<<dim3(N3C / 128, NROW / 128), 256, 0, stream>>>(
        xn, qkvw_b, qkvb, nullptr, qkvbuf, nullptr, nullptr, N3C, C_);
    // V transpose
    vtrans_kernel<<<dim3(T_ / 64, H_, B_), 256, 0, stream>>>(qkvbuf, vt);
    // fused attention
    attn_kernel<<<dim3(T_ / 16, H_, B_), 256, 0, stream>>>(qkvbuf, vt, bias, mask, attn_out, ybuf);
    // proj + residual*ls1 -> x1
    gemm_kernel<2><<<dim3(C_ / 128, NROW / 128), 256, 0, stream>>>(
        ybuf, projw_b, projb, x1, nullptr, x, ls1, C_, C_);
    // LN2
    ln_kernel<<<NROW, 256, 0, stream>>>(x1, ln2g, ln2b, xn);
    // MLP1 + gelu
    gemm_kernel<1><<<dim3(HID_ / 128, NROW / 128), 256, 0, stream>>>(
        xn, w1_b, b1, nullptr, g, nullptr, nullptr, HID_, C_);
    // MLP2 + residual*ls2 -> out
    gemm_kernel<2><<<dim3(C_ / 128, NROW / 128), 256, 0, stream>>>(
        g, w2_b, b2, outx, nullptr, x1, ls2, C_, HID_);
}